// Round 6
// baseline (83207.269 us; speedup 1.0000x reference)
//
#include <hip/hip_runtime.h>

#define NS 2058   // supersteps: 2048 + 2*5 skew

typedef __attribute__((ext_vector_type(4))) int   i32x4;
typedef __attribute__((ext_vector_type(8))) short s16x8;
typedef __attribute__((ext_vector_type(4))) float f32x4;

__device__ __forceinline__ unsigned short f2bf(float f) {
  unsigned u = __float_as_uint(f);
  unsigned r = u + 0x7FFFu + ((u >> 16) & 1u);
  return (unsigned short)(r >> 16);
}
__device__ __forceinline__ unsigned pack2bf(float lo, float hi) {
  return (unsigned)f2bf(lo) | ((unsigned)f2bf(hi) << 16);
}
__device__ __forceinline__ float bflo(unsigned u){ return __uint_as_float(u << 16); }
__device__ __forceinline__ float bfhi(unsigned u){ return __uint_as_float(u & 0xFFFF0000u); }

__device__ __forceinline__ float sigm(float x){ return 1.0f / (1.0f + __expf(-x)); }
__device__ __forceinline__ float tanh_(float x){
  float ax = fabsf(x);
  float e  = __expf(-2.0f * ax);
  float t  = (1.0f - e) / (1.0f + e);
  return copysignf(t, x);
}

// ---- LLC (cross-XCD) tagged atoms: proven-correct R4 path ----
__device__ __forceinline__ unsigned long long aload(const unsigned long long* p) {
  return __hip_atomic_load(p, __ATOMIC_RELAXED, __HIP_MEMORY_SCOPE_AGENT);
}
__device__ __forceinline__ void astore(unsigned long long* p, unsigned long long v) {
  __hip_atomic_store(p, v, __ATOMIC_RELAXED, __HIP_MEMORY_SCOPE_AGENT);
}

// ---- same-XCD fast path: sc0 = bypass L1, served by the XCD's shared L2 ----
__device__ __forceinline__ void l2ld(unsigned long long* d, const unsigned long long* p) {
  asm volatile("global_load_dwordx2 %0, %1, off sc0" : "=v"(*d) : "v"(p));
}
__device__ __forceinline__ void l2st(unsigned long long* p, unsigned long long v) {
  asm volatile("global_store_dwordx2 %0, %1, off sc0" :: "v"(p), "v"(v) : "memory");
}
__device__ __forceinline__ void vdrain() {            // rule-18 fence
  asm volatile("s_waitcnt vmcnt(0)" ::: "memory");
  __builtin_amdgcn_sched_barrier(0);
}

// ---------------- input projection ----------------
__global__ __launch_bounds__(256) void k_inproj(const float* __restrict__ x,
                                                const float* __restrict__ w,
                                                const float* __restrict__ bb,
                                                float* __restrict__ XP) {
  int idx = blockIdx.x * 256 + threadIdx.x;
  int b = idx >> 9, j = idx & 511;
  float acc = bb[j];
#pragma unroll
  for (int k = 0; k < 12; ++k) acc += x[b * 12 + k] * w[j * 12 + k];
  XP[idx] = acc;
}

// ---------------- layer-0 input gates (constant over t) ----------------
__global__ __launch_bounds__(256) void k_xg0(const float* __restrict__ XP,
                                             const float* __restrict__ Wih,
                                             const float* __restrict__ bih,
                                             float* __restrict__ XG0) {
  int idx = blockIdx.x * 256 + threadIdx.x;
  int b = idx & 31;
  int r = idx >> 5;
  const float* wr = Wih + (size_t)r * 512;
  const float* xr = XP + b * 512;
  float acc = bih[r];
  for (int k = 0; k < 512; k += 4) {
    const f32x4 w4 = *(const f32x4*)(wr + k);
    const f32x4 x4 = *(const f32x4*)(xr + k);
    acc += w4[0]*x4[0] + w4[1]*x4[1] + w4[2]*x4[2] + w4[3]*x4[3];
  }
  XG0[b * 2048 + r] = acc;
}

// ---------------- 6-layer pipelined scan, tag-in-data sync ----------------
// Grid 256: layer = bid&7 (round-robin => all 32 WGs of a layer share one XCD/L2),
// slot w = bid>>3; layers 6,7 exit. h: dual-published tagged u64 (sc0 L2 fast path
// + agent LLC safety net); consumer: bounded sc0 retry -> agent fallback. Mapping
// failure degrades to R4 speed, never hangs. Cross-layer Roll/Part/Prog: agent (LLC).
__global__ __launch_bounds__(256, 1) void k_pipe(
    const float* __restrict__ Wih, const float* __restrict__ Whh,
    const float* __restrict__ bih, const float* __restrict__ bhh,
    const float* __restrict__ lnS, const float* __restrict__ lnB,
    const float* __restrict__ XG0, const float* __restrict__ XP,
    unsigned long long* __restrict__ Hst,    // [6][2][8192] {tag, h pair}
    unsigned long long* __restrict__ Roll,   // [5][4][8192] {tag, out+res pair}
    unsigned long long* __restrict__ PartS,  // [5][4][32][32] {tag, f32 sum}
    unsigned long long* __restrict__ PartQ,  // [5][4][32][32] {tag, f32 sumsq}
    unsigned* __restrict__ RB,               // [32][2048][256] layer-5 rows
    unsigned* __restrict__ Prog)             // [6][32] consumer progress
{
  __shared__ char smem[65536];
  const int tid   = threadIdx.x;
  const int wgid  = blockIdx.x;
  const int layer = wgid & 7;    // XCD-aligned under round-robin dispatch
  const int w     = wgid >> 3;
  if (layer >= 6) return;        // WG-uniform exit

  char* xarea = smem;            // 32 KB: LN'd input row (l>=1) / L0 statics
  char* harea = smem + 32768;    // 32 KB: staged h; gacc at +16K (l>0); LN scratch rows 0-2
  const int lane = tid & 63;
  const int wv   = tid >> 6;     // wave = gate index
  const int j0   = w << 4;
  float* gacc = (float*)(layer == 0 ? (smem + 10240) : (harea + 16384));

  unsigned long long* HstL = Hst + layer * 16384;

  // ---- B-fragment preload ----
  s16x8 bfih[16], bfhh[16];
  {
    const int rcol = lane & 15;
    const int kg   = lane >> 4;
    const size_t rowbase = ((size_t)layer * 2048 + (size_t)(wv * 512 + j0 + rcol)) * 512;
    const float* ihr = Wih + rowbase;
    const float* hhr = Whh + rowbase;
#pragma unroll
    for (int kk = 0; kk < 16; ++kk) {
      const int k0 = kg * 8 + kk * 32;
      s16x8 v2;
#pragma unroll
      for (int j = 0; j < 8; ++j) v2[j] = (short)f2bf(hhr[k0 + j]);
      bfhh[kk] = v2;
      if (layer > 0) {
        s16x8 v1;
#pragma unroll
        for (int j = 0; j < 8; ++j) v1[j] = (short)f2bf(ihr[k0 + j]);
        bfih[kk] = v1;
      }
    }
  }

  const int ub = tid >> 3;            // batch row this thread updates
  const int jp = tid & 7;             // col-pair within WG
  const int kpglob = (j0 >> 1) + jp;  // global u32 pair index

  float bs[4][2];
#pragma unroll
  for (int g = 0; g < 4; ++g)
#pragma unroll
    for (int c = 0; c < 2; ++c) {
      const size_t r = (size_t)layer * 2048 + g * 512 + j0 + 2 * jp + c;
      float vv = bhh[r];
      if (layer > 0) vv += bih[r];    // L0: b_ih folded into XG0
      bs[g][c] = vv;
    }

  float sc0 = 0.f, sc1v = 0.f, bi0 = 0.f, bi1 = 0.f;
  if (layer > 0) {
    sc0  = lnS[(layer - 1) * 512 + 2 * tid];
    sc1v = lnS[(layer - 1) * 512 + 2 * tid + 1];
    bi0  = lnB[(layer - 1) * 512 + 2 * tid];
    bi1  = lnB[(layer - 1) * 512 + 2 * tid + 1];
  }

  if (layer == 0) {
    float* xg0s = (float*)smem;           // [4][32][16]
    float* xps  = (float*)(smem + 8192);  // [32][16]
    for (int i = tid; i < 2048; i += 256) {
      int g = i >> 9, b = (i >> 4) & 31, jl = i & 15;
      xg0s[i] = XG0[b * 2048 + g * 512 + j0 + jl];
    }
    for (int i = tid; i < 512; i += 256) {
      int b = i >> 4, jl = i & 15;
      xps[i] = XP[b * 512 + j0 + jl];
    }
  }
  __syncthreads();

  float xinc0 = 0.f, xinc1 = 0.f;
  if (layer == 0) {
    const float* xps = (const float*)(smem + 8192);
    xinc0 = xps[ub * 16 + 2 * jp];
    xinc1 = xps[ub * 16 + 2 * jp + 1];
  }

  const int rA  = lane & 15;
  const int kg2 = lane >> 4;
  const int swz = (rA & 7) << 4;
  const int ab0 = rA * 1024 + kg2 * 16;
  const int ab1 = ab0 + 16384;

  float creg0 = 0.f, creg1 = 0.f;
  unsigned myC = 0;                 // latched consumer-progress (layers<5)
  const int tbase = -2 * layer;
  const int lane31 = lane & 31;

#pragma unroll 1
  for (int s = 0; s < NS; ++s) {
    const int t = s + tbase;
    const bool act = (0 <= t) && (t < 2048);

    if (act) {
      // ---- back-pressure: Roll slot t&3 reusable when consumer prog >= t-4 ----
      if (layer < 5 && t >= 5) {
        const unsigned need = (unsigned)(t - 4);
        while (!__all((int)(myC >= need))) {
          if (myC < need)
            myC = __hip_atomic_load(Prog + (layer + 1) * 32 + lane31,
                                    __ATOMIC_RELAXED, __HIP_MEMORY_SCOPE_AGENT);
          if (!__all((int)(myC >= need))) __builtin_amdgcn_s_sleep(1);
        }
      }

      // ---- issue tagged h[t] loads via own-XCD L2 (sc0) ----
      const unsigned long long* hs = HstL + (size_t)(t & 1) * 8192;
      unsigned long long a[32];
#pragma unroll
      for (int it = 0; it < 32; ++it)
        l2ld(&a[it], hs + ((it + w) & 31) * 256 + tid);

      // ---- ih-MFMA from xarea (staged last superstep) overlaps h-load flight ----
      float xin0, xin1;
      f32x4 ai0 = {0.f,0.f,0.f,0.f}, ai1 = {0.f,0.f,0.f,0.f};
      if (layer > 0) {
        const unsigned xu = *(const unsigned*)(xarea + (((ub * 1024) + kpglob * 4) ^ ((ub & 7) << 4)));
        xin0 = bflo(xu); xin1 = bfhi(xu);
#pragma unroll
        for (int kk = 0; kk < 16; ++kk) {
          const i32x4 x0 = *(const i32x4*)(xarea + ((ab0 + kk * 64) ^ swz));
          const i32x4 x1 = *(const i32x4*)(xarea + ((ab1 + kk * 64) ^ swz));
          ai0 = __builtin_amdgcn_mfma_f32_16x16x32_bf16(__builtin_bit_cast(s16x8, x0), bfih[kk], ai0, 0, 0, 0);
          ai1 = __builtin_amdgcn_mfma_f32_16x16x32_bf16(__builtin_bit_cast(s16x8, x1), bfih[kk], ai1, 0, 0, 0);
        }
      } else { xin0 = xinc0; xin1 = xinc1; }

      // ---- tag-check: bounded sc0 laps, then guaranteed-convergent agent path ----
      vdrain();
      {
        const unsigned tagh = (unsigned)t;
        int lap = 0;
        for (;;) {
          bool bad = false;
#pragma unroll
          for (int it = 0; it < 32; ++it)
            if ((unsigned)(a[it] >> 32) != tagh) {
              if (lap < 64) l2ld(&a[it], hs + ((it + w) & 31) * 256 + tid);
              else          a[it] = aload(hs + ((it + w) & 31) * 256 + tid);
              bad = true;
            }
          if (!bad) break;
          if (lap < 64) vdrain();
          else if (lap > 96) __builtin_amdgcn_s_sleep(1);
          ++lap;
        }
      }

      // ---- stage h payloads into LDS (swizzled) ----
#pragma unroll
      for (int it = 0; it < 32; ++it) {
        const int q = (it + w) & 31;
        *(unsigned*)(harea + ((q * 1024 + tid * 4) ^ ((q & 7) << 4))) = (unsigned)a[it];
      }
      __syncthreads();   // (1) h staged

      f32x4 acc0, acc1;
      if (layer > 0) {
        f32x4 ah0 = {0.f,0.f,0.f,0.f}, ah1 = {0.f,0.f,0.f,0.f};
#pragma unroll
        for (int kk = 0; kk < 16; ++kk) {
          const i32x4 h0 = *(const i32x4*)(harea + ((ab0 + kk * 64) ^ swz));
          const i32x4 h1 = *(const i32x4*)(harea + ((ab1 + kk * 64) ^ swz));
          ah0 = __builtin_amdgcn_mfma_f32_16x16x32_bf16(__builtin_bit_cast(s16x8, h0), bfhh[kk], ah0, 0, 0, 0);
          ah1 = __builtin_amdgcn_mfma_f32_16x16x32_bf16(__builtin_bit_cast(s16x8, h1), bfhh[kk], ah1, 0, 0, 0);
        }
        acc0 = ai0 + ah0; acc1 = ai1 + ah1;
      } else {
        f32x4 a0a = {0.f,0.f,0.f,0.f}, a1a = {0.f,0.f,0.f,0.f};
        f32x4 a0b = {0.f,0.f,0.f,0.f}, a1b = {0.f,0.f,0.f,0.f};
#pragma unroll
        for (int kk = 0; kk < 8; ++kk) {
          const i32x4 h0a = *(const i32x4*)(harea + ((ab0 + kk * 64) ^ swz));
          const i32x4 h1a = *(const i32x4*)(harea + ((ab1 + kk * 64) ^ swz));
          const i32x4 h0b = *(const i32x4*)(harea + ((ab0 + (kk + 8) * 64) ^ swz));
          const i32x4 h1b = *(const i32x4*)(harea + ((ab1 + (kk + 8) * 64) ^ swz));
          a0a = __builtin_amdgcn_mfma_f32_16x16x32_bf16(__builtin_bit_cast(s16x8, h0a), bfhh[kk], a0a, 0, 0, 0);
          a1a = __builtin_amdgcn_mfma_f32_16x16x32_bf16(__builtin_bit_cast(s16x8, h1a), bfhh[kk], a1a, 0, 0, 0);
          a0b = __builtin_amdgcn_mfma_f32_16x16x32_bf16(__builtin_bit_cast(s16x8, h0b), bfhh[kk + 8], a0b, 0, 0, 0);
          a1b = __builtin_amdgcn_mfma_f32_16x16x32_bf16(__builtin_bit_cast(s16x8, h1b), bfhh[kk + 8], a1b, 0, 0, 0);
        }
        acc0 = a0a + a0b; acc1 = a1a + a1b;
      }
      __syncthreads();   // (2) harea reads done (gacc aliases staged rows 16-25)
      {
        float* gp = gacc + (wv * 16 + rA) * 36 + kg2 * 4;
        *(f32x4*)gp        = acc0;
        *(f32x4*)(gp + 16) = acc1;
      }
      __syncthreads();   // (3)

      float pre[4][2];
#pragma unroll
      for (int g = 0; g < 4; ++g)
#pragma unroll
        for (int c = 0; c < 2; ++c) {
          float vv = gacc[(g * 16 + 2 * jp + c) * 36 + ub] + bs[g][c];
          if (layer == 0) vv += ((const float*)smem)[(g * 32 + ub) * 16 + 2 * jp + c];
          pre[g][c] = vv;
        }

      float i0 = sigm(pre[0][0]), ff0 = sigm(pre[1][0]), g0 = tanh_(pre[2][0]), o0 = sigm(pre[3][0]);
      creg0 = ff0 * creg0 + i0 * g0;
      float h0 = o0 * tanh_(creg0);
      float i1 = sigm(pre[0][1]), ff1 = sigm(pre[1][1]), g1 = tanh_(pre[2][1]), o1 = sigm(pre[3][1]);
      creg1 = ff1 * creg1 + i1 * g1;
      float h1 = o1 * tanh_(creg1);
      const float out0 = h0 + xin0, out1 = h1 + xin1;
      const unsigned long long tago = ((unsigned long long)(unsigned)(t + 1)) << 32;

      if (layer < 5) {
        float sP  = out0 + out1;
        float ssP = out0 * out0 + out1 * out1;
#pragma unroll
        for (int m = 1; m < 8; m <<= 1) { sP += __shfl_xor(sP, m, 64); ssP += __shfl_xor(ssP, m, 64); }
        astore(Roll + layer * 32768 + (size_t)(t & 3) * 8192 + ub * 256 + kpglob,
               tago | pack2bf(out0, out1));
        if (jp == 0) {
          const size_t pi = layer * 4096 + (size_t)(t & 3) * 1024 + w * 32 + ub;
          astore(PartS + pi, tago | __float_as_uint(sP));
          astore(PartQ + pi, tago | __float_as_uint(ssP));
        }
      } else {
        RB[((size_t)ub * 2048 + t) * 256 + kpglob] = pack2bf(out0, out1);
      }
      {
        unsigned long long* hp = HstL + (size_t)((t + 1) & 1) * 8192 + (ub << 8) + kpglob;
        const unsigned long long hv = tago | pack2bf(h0, h1);
        l2st(hp, hv);    // fast path: own-XCD L2 (same-layer consumers)
        astore(hp, hv);  // safety net: LLC (agent fallback readers)
      }
    }

    // ===== phase D: prefetch + LN-stage next input row =====
    const int r = s + 1 + tbase;
    if (layer > 0 && 0 <= r && r < 2048) {
      const unsigned long long* RollC = Roll + (layer - 1) * 32768 + (size_t)(r & 3) * 8192;
      unsigned long long xr[32];
#pragma unroll
      for (int i = 0; i < 32; ++i) {
        const int q = (i + w) & 31;
        xr[i] = aload(RollC + q * 256 + tid);
      }
      const int b = tid & 31, w8 = tid >> 5;
      const unsigned long long* PSc = PartS + (layer - 1) * 4096 + (size_t)(r & 3) * 1024;
      const unsigned long long* PQc = PartQ + (layer - 1) * 4096 + (size_t)(r & 3) * 1024;
      unsigned long long ps[4], pq[4];
#pragma unroll
      for (int k = 0; k < 4; ++k) {
        ps[k] = aload(PSc + (w8 + 8 * k) * 32 + b);
        pq[k] = aload(PQc + (w8 + 8 * k) * 32 + b);
      }
      const unsigned tagr = (unsigned)(r + 1);
      for (;;) {
        bool bad = false;
#pragma unroll
        for (int i = 0; i < 32; ++i)
          if ((unsigned)(xr[i] >> 32) != tagr) {
            const int q = (i + w) & 31;
            xr[i] = aload(RollC + q * 256 + tid);
            bad = true;
          }
#pragma unroll
        for (int k = 0; k < 4; ++k) {
          if ((unsigned)(ps[k] >> 32) != tagr) { ps[k] = aload(PSc + (w8 + 8 * k) * 32 + b); bad = true; }
          if ((unsigned)(pq[k] >> 32) != tagr) { pq[k] = aload(PQc + (w8 + 8 * k) * 32 + b); bad = true; }
        }
        if (!bad) break;
      }
      float s4 = 0.f, ss4 = 0.f;
#pragma unroll
      for (int k = 0; k < 4; ++k) {
        s4  += __uint_as_float((unsigned)ps[k]);
        ss4 += __uint_as_float((unsigned)pq[k]);
      }
      float* scr = (float*)harea;            // [8][32][2], disjoint from gacc(+16K)
      scr[(w8 * 32 + b) * 2]     = s4;
      scr[(w8 * 32 + b) * 2 + 1] = ss4;
      __syncthreads();   // D1
      float* stats = (float*)(harea + 2048); // [32][2] = {mu, rs}
      if (tid < 32) {
        const float* sc = (const float*)harea;
        float ssum = 0.f, sssum = 0.f;
#pragma unroll
        for (int k = 0; k < 8; ++k) { ssum += sc[(k * 32 + tid) * 2]; sssum += sc[(k * 32 + tid) * 2 + 1]; }
        const float mu = ssum * (1.f / 512.f);
        float var = sssum * (1.f / 512.f) - mu * mu;
        stats[tid * 2]     = mu;
        stats[tid * 2 + 1] = rsqrtf(var + 1e-5f);
      }
      __syncthreads();   // D2
#pragma unroll
      for (int i = 0; i < 32; ++i) {
        const int q = (i + w) & 31;
        const float mu = stats[q * 2], rs = stats[q * 2 + 1];
        const unsigned u = (unsigned)xr[i];
        const float av = (bflo(u) - mu) * rs * sc0  + bi0;
        const float bv = (bfhi(u) - mu) * rs * sc1v + bi1;
        *(unsigned*)(xarea + ((q * 1024 + tid * 4) ^ ((q & 7) << 4))) = pack2bf(av, bv);
      }
    }

    // ---- publish progress (consumers certify Roll rows <= t+1 consumed) ----
    if (layer > 0 && act && tid == 0)
      __hip_atomic_store(Prog + layer * 32 + w, (unsigned)(t + 1),
                         __ATOMIC_RELAXED, __HIP_MEMORY_SCOPE_AGENT);

    __syncthreads();   // (5) xarea/LDS writes visible before next iteration
  }
}

// ---------------- fused final LayerNorm + output head ----------------
__global__ __launch_bounds__(256) void k_lnout(const unsigned* __restrict__ Rin,
                                               const float* __restrict__ lnS,
                                               const float* __restrict__ lnB,
                                               const float* __restrict__ ow,
                                               const float* __restrict__ ob,
                                               float* __restrict__ y) {
  int row  = blockIdx.x * 4 + (threadIdx.x >> 6);
  int lane = threadIdx.x & 63;
  const i32x4 v = *(const i32x4*)(Rin + (size_t)row * 256 + lane * 4);
  float xv[8];
#pragma unroll
  for (int j = 0; j < 4; ++j) {
    unsigned u = (unsigned)v[j];
    xv[2*j]   = bflo(u);
    xv[2*j+1] = bfhi(u);
  }
  float s = 0.f, s2 = 0.f;
#pragma unroll
  for (int j = 0; j < 8; ++j) { s += xv[j]; s2 += xv[j] * xv[j]; }
#pragma unroll
  for (int m = 1; m < 64; m <<= 1) { s += __shfl_xor(s, m, 64); s2 += __shfl_xor(s2, m, 64); }
  float mu  = s * (1.f / 512.f);
  float var = s2 * (1.f / 512.f) - mu * mu;
  float rs  = rsqrtf(var + 1e-5f);
  const float* Sp = lnS + 5 * 512 + lane * 8;
  const float* Bp = lnB + 5 * 512 + lane * 8;
  const float* wp = ow + lane * 8;
  float acc = 0.f;
#pragma unroll
  for (int j = 0; j < 8; ++j)
    acc += ((xv[j] - mu) * rs * Sp[j] + Bp[j]) * wp[j];
#pragma unroll
  for (int m = 1; m < 64; m <<= 1) acc += __shfl_xor(acc, m, 64);
  if (lane == 0) y[row] = acc + ob[0];
}

extern "C" void kernel_launch(void* const* d_in, const int* in_sizes, int n_in,
                              void* d_out, int out_size, void* d_ws, size_t ws_size,
                              hipStream_t stream) {
  (void)in_sizes; (void)n_in; (void)out_size; (void)ws_size;
  const float* x   = (const float*)d_in[0];
  const float* ipw = (const float*)d_in[1];
  const float* ipb = (const float*)d_in[2];
  const float* Wih = (const float*)d_in[3];
  const float* Whh = (const float*)d_in[4];
  const float* bih = (const float*)d_in[5];
  const float* bhh = (const float*)d_in[6];
  const float* lnS = (const float*)d_in[7];
  const float* lnB = (const float*)d_in[8];
  const float* ow  = (const float*)d_in[9];
  const float* ob  = (const float*)d_in[10];
  float* y = (float*)d_out;

  char* ws = (char*)d_ws;
  unsigned* Prog            = (unsigned*)ws;                         // 768 B
  float* XP                 = (float*)(ws + 4096);                   // 64 KB
  float* XG0                = (float*)(ws + 69632);                  // 256 KB
  unsigned long long* Hst   = (unsigned long long*)(ws + 331776);    // 768 KB
  unsigned long long* Roll  = (unsigned long long*)(ws + 1118208);   // 1.25 MB
  unsigned long long* PartS = (unsigned long long*)(ws + 2428928);   // 160 KB
  unsigned long long* PartQ = (unsigned long long*)(ws + 2592768);   // 160 KB
  unsigned* RB              = (unsigned*)(ws + 4194304);             // 67.1 MB

  hipMemsetAsync(Prog, 0, 768, stream);
  hipMemsetAsync(Hst, 0, 786432, stream);
  k_inproj<<<64, 256, 0, stream>>>(x, ipw, ipb, XP);
  k_xg0<<<256, 256, 0, stream>>>(XP, Wih, bih, XG0);
  k_pipe<<<256, 256, 0, stream>>>(Wih, Whh, bih, bhh, lnS, lnB, XG0, XP,
                                  Hst, Roll, PartS, PartQ, RB, Prog);
  k_lnout<<<16384, 256, 0, stream>>>(RB, lnS, lnB, ow, ob, y);
}

// Round 8
// 18248.801 us; speedup vs baseline: 4.5596x; 4.5596x over previous
//
#include <hip/hip_runtime.h>

typedef __attribute__((ext_vector_type(4))) int   i32x4;
typedef __attribute__((ext_vector_type(8))) short s16x8;
typedef __attribute__((ext_vector_type(4))) float f32x4;

__device__ __forceinline__ unsigned short f2bf(float f) {
  unsigned u = __float_as_uint(f);
  unsigned r = u + 0x7FFFu + ((u >> 16) & 1u);
  return (unsigned short)(r >> 16);
}
__device__ __forceinline__ unsigned pack2bf(float lo, float hi) {
  return (unsigned)f2bf(lo) | ((unsigned)f2bf(hi) << 16);
}
__device__ __forceinline__ float bflo(unsigned u){ return __uint_as_float(u << 16); }
__device__ __forceinline__ float bfhi(unsigned u){ return __uint_as_float(u & 0xFFFF0000u); }

__device__ __forceinline__ float sigm(float x){ return 1.0f / (1.0f + __expf(-x)); }
__device__ __forceinline__ float tanh_(float x){
  float ax = fabsf(x);
  float e  = __expf(-2.0f * ax);
  float t  = (1.0f - e) / (1.0f + e);
  return copysignf(t, x);
}

__device__ __forceinline__ unsigned long long aload(const unsigned long long* p) {
  return __hip_atomic_load(p, __ATOMIC_RELAXED, __HIP_MEMORY_SCOPE_AGENT);
}
__device__ __forceinline__ void astore32(unsigned* p, unsigned v) {
  __hip_atomic_store(p, v, __ATOMIC_RELAXED, __HIP_MEMORY_SCOPE_AGENT);
}
__device__ __forceinline__ void astore64(unsigned long long* p, unsigned long long v) {
  __hip_atomic_store(p, v, __ATOMIC_RELAXED, __HIP_MEMORY_SCOPE_AGENT);
}

// All 4 waves spin independently: lanes 0-31 each watch one 64B-padded flag.
__device__ __forceinline__ void waitflags(const unsigned* Flg, int base, unsigned need, int lane) {
  const unsigned* p = Flg + ((base + (lane & 31)) << 4);
  unsigned v = __hip_atomic_load(p, __ATOMIC_RELAXED, __HIP_MEMORY_SCOPE_AGENT);
  while (!__all((int)(v >= need))) {
    __builtin_amdgcn_s_sleep(1);
    v = __hip_atomic_load(p, __ATOMIC_RELAXED, __HIP_MEMORY_SCOPE_AGENT);
  }
}

// ---------------- input projection ----------------
__global__ __launch_bounds__(256) void k_inproj(const float* __restrict__ x,
                                                const float* __restrict__ w,
                                                const float* __restrict__ bb,
                                                float* __restrict__ XP) {
  int idx = blockIdx.x * 256 + threadIdx.x;
  int b = idx >> 9, j = idx & 511;
  float acc = bb[j];
#pragma unroll
  for (int k = 0; k < 12; ++k) acc += x[b * 12 + k] * w[j * 12 + k];
  XP[idx] = acc;
}

// ---------------- layer-0 input gates (constant over t) ----------------
__global__ __launch_bounds__(256) void k_xg0(const float* __restrict__ XP,
                                             const float* __restrict__ Wih,
                                             const float* __restrict__ bih,
                                             float* __restrict__ XG0) {
  int idx = blockIdx.x * 256 + threadIdx.x;
  int b = idx & 31;
  int r = idx >> 5;
  const float* wr = Wih + (size_t)r * 512;
  const float* xr = XP + b * 512;
  float acc = bih[r];
  for (int k = 0; k < 512; k += 4) {
    const f32x4 w4 = *(const f32x4*)(wr + k);
    const f32x4 x4 = *(const f32x4*)(xr + k);
    acc += w4[0]*x4[0] + w4[1]*x4[1] + w4[2]*x4[2] + w4[3]*x4[3];
  }
  XG0[b * 2048 + r] = acc;
}

// ---------------- 6-layer pipelined scan, layer-local flag sync ----------------
// 192 WGs: layer = wgid>>5, w = wgid&31 owns h-cols [16w,16w+16). Layers free-run:
// own-layer flags gate h (32-WG barrier, R2-proven); producer-layer flags gate
// Roll/Part reads; Prog latch back-pressures producers. All payloads untagged
// relaxed agent atomics (LLC-coherent), visibility certified by release flags.
// R7 deadlock fix: flag publish is UNCONDITIONAL (max flag 2049, so phase D's
// wait for t+3 at t=2046 terminates).
__global__ __launch_bounds__(256, 1) void k_pipe(
    const float* __restrict__ Wih, const float* __restrict__ Whh,
    const float* __restrict__ bih, const float* __restrict__ bhh,
    const float* __restrict__ lnS, const float* __restrict__ lnB,
    const float* __restrict__ XG0, const float* __restrict__ XP,
    unsigned long long* __restrict__ Hst,    // [6][2][4096] u64 (2 bf16-pairs)
    unsigned long long* __restrict__ Roll,   // [5][4][4096] u64
    unsigned long long* __restrict__ Part,   // [5][4][32][32] u64 {f32 sum, f32 sumsq}
    unsigned* __restrict__ RB,               // [32][2048][256] layer-5 rows
    unsigned* __restrict__ Flg,              // [192] stride-16 (64B padded)
    unsigned* __restrict__ Prog)             // [192] stride-16
{
  __shared__ char smem[65536];
  const int tid   = threadIdx.x;
  const int wgid  = blockIdx.x;
  const int layer = wgid >> 5;
  const int w     = wgid & 31;

  char* xarea = smem;            // 32 KB: LN'd input row (l>=1) / L0 statics
  char* harea = smem + 32768;    // 32 KB: staged h; gacc at +16K (l>0); LN scratch rows 0-2
  const int lane = tid & 63;
  const int wv   = tid >> 6;     // wave = gate index
  const int j0   = w << 4;
  float* gacc = (float*)(layer == 0 ? (smem + 10240) : (harea + 16384));

  unsigned long long* HstL = Hst + layer * 8192;

  // ---- B-fragment preload ----
  s16x8 bfih[16], bfhh[16];
  {
    const int rcol = lane & 15;
    const int kg   = lane >> 4;
    const size_t rowbase = ((size_t)layer * 2048 + (size_t)(wv * 512 + j0 + rcol)) * 512;
    const float* ihr = Wih + rowbase;
    const float* hhr = Whh + rowbase;
#pragma unroll
    for (int kk = 0; kk < 16; ++kk) {
      const int k0 = kg * 8 + kk * 32;
      s16x8 v2;
#pragma unroll
      for (int j = 0; j < 8; ++j) v2[j] = (short)f2bf(hhr[k0 + j]);
      bfhh[kk] = v2;
      if (layer > 0) {
        s16x8 v1;
#pragma unroll
        for (int j = 0; j < 8; ++j) v1[j] = (short)f2bf(ihr[k0 + j]);
        bfih[kk] = v1;
      }
    }
  }

  const int ub = tid >> 3;            // batch row this thread updates
  const int jp = tid & 7;             // col-pair within WG
  const int kpglob = (j0 >> 1) + jp;  // global u32 pair index

  float bs[4][2];
#pragma unroll
  for (int g = 0; g < 4; ++g)
#pragma unroll
    for (int c = 0; c < 2; ++c) {
      const size_t r = (size_t)layer * 2048 + g * 512 + j0 + 2 * jp + c;
      float vv = bhh[r];
      if (layer > 0) vv += bih[r];    // L0: b_ih folded into XG0
      bs[g][c] = vv;
    }

  // LN params for this thread's phase-D columns: bf16 cols 4*(tid&127)..+3
  float scp[4] = {0,0,0,0}, bip[4] = {0,0,0,0};
  if (layer > 0) {
    const int cb = (layer - 1) * 512 + 4 * (tid & 127);
#pragma unroll
    for (int j = 0; j < 4; ++j) { scp[j] = lnS[cb + j]; bip[j] = lnB[cb + j]; }
  }

  if (layer == 0) {
    float* xg0s = (float*)smem;           // [4][32][16]
    float* xps  = (float*)(smem + 8192);  // [32][16]
    for (int i = tid; i < 2048; i += 256) {
      int g = i >> 9, b = (i >> 4) & 31, jl = i & 15;
      xg0s[i] = XG0[b * 2048 + g * 512 + j0 + jl];
    }
    for (int i = tid; i < 512; i += 256) {
      int b = i >> 4, jl = i & 15;
      xps[i] = XP[b * 512 + j0 + jl];
    }
  }

  // ---- h0 = 0 into slot 0; publish flag = 1 ----
  astore32((unsigned*)HstL + (ub << 8) + kpglob, 0u);
  __syncthreads();   // drains vmcnt: zero-stores visible before flag
  if (tid == 0)
    __hip_atomic_store(Flg + ((layer * 32 + w) << 4), 1u, __ATOMIC_RELEASE, __HIP_MEMORY_SCOPE_AGENT);

  float xinc0 = 0.f, xinc1 = 0.f;
  if (layer == 0) {
    const float* xps = (const float*)(smem + 8192);
    xinc0 = xps[ub * 16 + 2 * jp];
    xinc1 = xps[ub * 16 + 2 * jp + 1];
  }

  const int b31 = tid & 31, w8 = tid >> 5;

  // ---- pre-loop blocking LN-stage of row 0 (layer>0): producer flag >= 2 ----
  if (layer > 0) {
    waitflags(Flg, (layer - 1) * 32, 2u, lane);
    const unsigned long long* RollC = Roll + (layer - 1) * 16384;   // slot 0
    const unsigned long long* PC    = Part + (layer - 1) * 4096;
    unsigned long long xr[16], pr[4];
#pragma unroll
    for (int it = 0; it < 16; ++it) xr[it] = aload(RollC + it * 256 + tid);
#pragma unroll
    for (int k = 0; k < 4; ++k) pr[k] = aload(PC + (w8 + 8 * k) * 32 + b31);
    float s4 = 0.f, ss4 = 0.f;
#pragma unroll
    for (int k = 0; k < 4; ++k) { s4 += __uint_as_float((unsigned)pr[k]); ss4 += __uint_as_float((unsigned)(pr[k] >> 32)); }
    float* scr = (float*)harea;
    scr[(w8 * 32 + b31) * 2]     = s4;
    scr[(w8 * 32 + b31) * 2 + 1] = ss4;
    __syncthreads();
    float* stats = (float*)(harea + 2048);
    if (tid < 32) {
      const float* sc = (const float*)harea;
      float ssum = 0.f, sssum = 0.f;
#pragma unroll
      for (int k = 0; k < 8; ++k) { ssum += sc[(k * 32 + tid) * 2]; sssum += sc[(k * 32 + tid) * 2 + 1]; }
      const float mu = ssum * (1.f / 512.f);
      float var = sssum * (1.f / 512.f) - mu * mu;
      stats[tid * 2] = mu; stats[tid * 2 + 1] = rsqrtf(var + 1e-5f);
    }
    __syncthreads();
#pragma unroll
    for (int it = 0; it < 16; ++it) {
      const int flat = it * 256 + tid;
      const int q = flat >> 7, c0 = (flat & 127) * 2;
      const float mu = stats[q * 2], rs = stats[q * 2 + 1];
      const unsigned lo = (unsigned)xr[it], hi = (unsigned)(xr[it] >> 32);
      const float a0 = (bflo(lo) - mu) * rs * scp[0] + bip[0];
      const float a1 = (bfhi(lo) - mu) * rs * scp[1] + bip[1];
      const float a2 = (bflo(hi) - mu) * rs * scp[2] + bip[2];
      const float a3 = (bfhi(hi) - mu) * rs * scp[3] + bip[3];
      *(unsigned long long*)(xarea + ((q * 1024 + c0 * 4) ^ ((q & 7) << 4))) =
          (unsigned long long)pack2bf(a0, a1) | ((unsigned long long)pack2bf(a2, a3) << 32);
    }
  }
  __syncthreads();

  const int rA  = lane & 15;
  const int kg2 = lane >> 4;
  const int swz = (rA & 7) << 4;
  const int ab0 = rA * 1024 + kg2 * 16;
  const int ab1 = ab0 + 16384;

  float creg0 = 0.f, creg1 = 0.f;
  unsigned myC = 0;                 // latched consumer-progress (layers<5)
  const int lane31 = lane & 31;

#pragma unroll 1
  for (int t = 0; t < 2048; ++t) {
    // (a) back-pressure: Roll slot t&3 reusable when consumer prog >= t-4
    if (layer < 5 && t >= 5) {
      const unsigned need = (unsigned)(t - 4);
      while (!__all((int)(myC >= need))) {
        if (myC < need)
          myC = __hip_atomic_load(Prog + (((layer + 1) * 32 + lane31) << 4),
                                  __ATOMIC_RELAXED, __HIP_MEMORY_SCOPE_AGENT);
        if (!__all((int)(myC >= need))) __builtin_amdgcn_s_sleep(1);
      }
    }

    // (b) own-layer barrier: peers stored h for step t (flag >= t+1)
    waitflags(Flg, layer * 32, (unsigned)(t + 1), lane);

    // (c) issue untagged h loads (16 u64/thread, LLC)
    const unsigned long long* hs = HstL + (size_t)(t & 1) * 4096;
    unsigned long long a[16];
#pragma unroll
    for (int it = 0; it < 16; ++it)
      a[it] = aload(hs + it * 256 + tid);

    // (d) ih-MFMA from xarea overlaps h-load flight
    float xin0, xin1;
    f32x4 ai0 = {0.f,0.f,0.f,0.f}, ai1 = {0.f,0.f,0.f,0.f};
    if (layer > 0) {
      const unsigned xu = *(const unsigned*)(xarea + (((ub * 1024) + kpglob * 4) ^ ((ub & 7) << 4)));
      xin0 = bflo(xu); xin1 = bfhi(xu);
#pragma unroll
      for (int kk = 0; kk < 16; ++kk) {
        const i32x4 x0 = *(const i32x4*)(xarea + ((ab0 + kk * 64) ^ swz));
        const i32x4 x1 = *(const i32x4*)(xarea + ((ab1 + kk * 64) ^ swz));
        ai0 = __builtin_amdgcn_mfma_f32_16x16x32_bf16(__builtin_bit_cast(s16x8, x0), bfih[kk], ai0, 0, 0, 0);
        ai1 = __builtin_amdgcn_mfma_f32_16x16x32_bf16(__builtin_bit_cast(s16x8, x1), bfih[kk], ai1, 0, 0, 0);
      }
    } else { xin0 = xinc0; xin1 = xinc1; }

    // (e) stage h payloads into LDS (swizzled)
#pragma unroll
    for (int it = 0; it < 16; ++it) {
      const int flat = it * 256 + tid;
      const int q = flat >> 7, kp2 = flat & 127;
      *(unsigned long long*)(harea + ((q * 1024 + kp2 * 8) ^ ((q & 7) << 4))) = a[it];
    }
    __syncthreads();   // (1) h staged

    f32x4 acc0, acc1;
    if (layer > 0) {
      f32x4 ah0 = {0.f,0.f,0.f,0.f}, ah1 = {0.f,0.f,0.f,0.f};
#pragma unroll
      for (int kk = 0; kk < 16; ++kk) {
        const i32x4 h0 = *(const i32x4*)(harea + ((ab0 + kk * 64) ^ swz));
        const i32x4 h1 = *(const i32x4*)(harea + ((ab1 + kk * 64) ^ swz));
        ah0 = __builtin_amdgcn_mfma_f32_16x16x32_bf16(__builtin_bit_cast(s16x8, h0), bfhh[kk], ah0, 0, 0, 0);
        ah1 = __builtin_amdgcn_mfma_f32_16x16x32_bf16(__builtin_bit_cast(s16x8, h1), bfhh[kk], ah1, 0, 0, 0);
      }
      acc0 = ai0 + ah0; acc1 = ai1 + ah1;
    } else {
      f32x4 a0a = {0.f,0.f,0.f,0.f}, a1a = {0.f,0.f,0.f,0.f};
      f32x4 a0b = {0.f,0.f,0.f,0.f}, a1b = {0.f,0.f,0.f,0.f};
#pragma unroll
      for (int kk = 0; kk < 8; ++kk) {
        const i32x4 h0a = *(const i32x4*)(harea + ((ab0 + kk * 64) ^ swz));
        const i32x4 h1a = *(const i32x4*)(harea + ((ab1 + kk * 64) ^ swz));
        const i32x4 h0b = *(const i32x4*)(harea + ((ab0 + (kk + 8) * 64) ^ swz));
        const i32x4 h1b = *(const i32x4*)(harea + ((ab1 + (kk + 8) * 64) ^ swz));
        a0a = __builtin_amdgcn_mfma_f32_16x16x32_bf16(__builtin_bit_cast(s16x8, h0a), bfhh[kk], a0a, 0, 0, 0);
        a1a = __builtin_amdgcn_mfma_f32_16x16x32_bf16(__builtin_bit_cast(s16x8, h1a), bfhh[kk], a1a, 0, 0, 0);
        a0b = __builtin_amdgcn_mfma_f32_16x16x32_bf16(__builtin_bit_cast(s16x8, h0b), bfhh[kk + 8], a0b, 0, 0, 0);
        a1b = __builtin_amdgcn_mfma_f32_16x16x32_bf16(__builtin_bit_cast(s16x8, h1b), bfhh[kk + 8], a1b, 0, 0, 0);
      }
      acc0 = a0a + a0b; acc1 = a1a + a1b;
    }
    __syncthreads();   // (2) harea reads done (gacc aliases staged rows 16-25)
    {
      float* gp = gacc + (wv * 16 + rA) * 36 + kg2 * 4;
      *(f32x4*)gp        = acc0;
      *(f32x4*)(gp + 16) = acc1;
    }
    __syncthreads();   // (3)

    float pre[4][2];
#pragma unroll
    for (int g = 0; g < 4; ++g)
#pragma unroll
      for (int c = 0; c < 2; ++c) {
        float vv = gacc[(g * 16 + 2 * jp + c) * 36 + ub] + bs[g][c];
        if (layer == 0) vv += ((const float*)smem)[(g * 32 + ub) * 16 + 2 * jp + c];
        pre[g][c] = vv;
      }

    float i0 = sigm(pre[0][0]), ff0 = sigm(pre[1][0]), g0 = tanh_(pre[2][0]), o0 = sigm(pre[3][0]);
    creg0 = ff0 * creg0 + i0 * g0;
    float h0 = o0 * tanh_(creg0);
    float i1 = sigm(pre[0][1]), ff1 = sigm(pre[1][1]), g1 = tanh_(pre[2][1]), o1 = sigm(pre[3][1]);
    creg1 = ff1 * creg1 + i1 * g1;
    float h1 = o1 * tanh_(creg1);
    const float out0 = h0 + xin0, out1 = h1 + xin1;

    if (layer < 5) {
      float sP  = out0 + out1;
      float ssP = out0 * out0 + out1 * out1;
#pragma unroll
      for (int m = 1; m < 8; m <<= 1) { sP += __shfl_xor(sP, m, 64); ssP += __shfl_xor(ssP, m, 64); }
      astore32((unsigned*)(Roll + layer * 16384 + (size_t)(t & 3) * 4096) + (ub << 8) + kpglob,
               pack2bf(out0, out1));
      if (jp == 0)
        astore64(Part + layer * 4096 + (size_t)(t & 3) * 1024 + w * 32 + ub,
                 (unsigned long long)__float_as_uint(sP) |
                 ((unsigned long long)__float_as_uint(ssP) << 32));
    } else {
      RB[((size_t)ub * 2048 + t) * 256 + kpglob] = pack2bf(out0, out1);
    }
    astore32((unsigned*)(HstL + (size_t)((t + 1) & 1) * 4096) + (ub << 8) + kpglob,
             pack2bf(h0, h1));

    __syncthreads();   // (4) all threads' stores drained (vmcnt) before flag
    if (tid == 0)      // UNCONDITIONAL publish (R7 fix): last flag = 2049
      __hip_atomic_store(Flg + ((layer * 32 + w) << 4), (unsigned)(t + 2),
                         __ATOMIC_RELEASE, __HIP_MEMORY_SCOPE_AGENT);

    // ===== phase D: wait producer, load + LN-stage row t+1 =====
    if (layer > 0 && t < 2047) {
      waitflags(Flg, (layer - 1) * 32, (unsigned)(t + 3), lane);
      const unsigned long long* RollC = Roll + (layer - 1) * 16384 + (size_t)((t + 1) & 3) * 4096;
      const unsigned long long* PC    = Part + (layer - 1) * 4096 + (size_t)((t + 1) & 3) * 1024;
      unsigned long long xr[16], pr[4];
#pragma unroll
      for (int it = 0; it < 16; ++it) xr[it] = aload(RollC + it * 256 + tid);
#pragma unroll
      for (int k = 0; k < 4; ++k) pr[k] = aload(PC + (w8 + 8 * k) * 32 + b31);
      float s4 = 0.f, ss4 = 0.f;
#pragma unroll
      for (int k = 0; k < 4; ++k) { s4 += __uint_as_float((unsigned)pr[k]); ss4 += __uint_as_float((unsigned)(pr[k] >> 32)); }
      float* scr = (float*)harea;            // rows 0-2, disjoint from gacc(+16K)
      scr[(w8 * 32 + b31) * 2]     = s4;
      scr[(w8 * 32 + b31) * 2 + 1] = ss4;
      __syncthreads();   // D1 (also completes xr into registers)
      float* stats = (float*)(harea + 2048);
      if (tid < 32) {
        const float* sc = (const float*)harea;
        float ssum = 0.f, sssum = 0.f;
#pragma unroll
        for (int k = 0; k < 8; ++k) { ssum += sc[(k * 32 + tid) * 2]; sssum += sc[(k * 32 + tid) * 2 + 1]; }
        const float mu = ssum * (1.f / 512.f);
        float var = sssum * (1.f / 512.f) - mu * mu;
        stats[tid * 2] = mu; stats[tid * 2 + 1] = rsqrtf(var + 1e-5f);
      }
      __syncthreads();   // D2
#pragma unroll
      for (int it = 0; it < 16; ++it) {
        const int flat = it * 256 + tid;
        const int q = flat >> 7, c0 = (flat & 127) * 2;
        const float mu = stats[q * 2], rs = stats[q * 2 + 1];
        const unsigned lo = (unsigned)xr[it], hi = (unsigned)(xr[it] >> 32);
        const float a0 = (bflo(lo) - mu) * rs * scp[0] + bip[0];
        const float a1 = (bfhi(lo) - mu) * rs * scp[1] + bip[1];
        const float a2 = (bflo(hi) - mu) * rs * scp[2] + bip[2];
        const float a3 = (bfhi(hi) - mu) * rs * scp[3] + bip[3];
        *(unsigned long long*)(xarea + ((q * 1024 + c0 * 4) ^ ((q & 7) << 4))) =
            (unsigned long long)pack2bf(a0, a1) | ((unsigned long long)pack2bf(a2, a3) << 32);
      }
      if (tid == 0)
        astore32(Prog + ((layer * 32 + w) << 4), (unsigned)(t + 1));
    }

    __syncthreads();   // (5) xarea ready; gacc reads done before next h-stage
  }
}

// ---------------- fused final LayerNorm + output head ----------------
__global__ __launch_bounds__(256) void k_lnout(const unsigned* __restrict__ Rin,
                                               const float* __restrict__ lnS,
                                               const float* __restrict__ lnB,
                                               const float* __restrict__ ow,
                                               const float* __restrict__ ob,
                                               float* __restrict__ y) {
  int row  = blockIdx.x * 4 + (threadIdx.x >> 6);
  int lane = threadIdx.x & 63;
  const i32x4 v = *(const i32x4*)(Rin + (size_t)row * 256 + lane * 4);
  float xv[8];
#pragma unroll
  for (int j = 0; j < 4; ++j) {
    unsigned u = (unsigned)v[j];
    xv[2*j]   = bflo(u);
    xv[2*j+1] = bfhi(u);
  }
  float s = 0.f, s2 = 0.f;
#pragma unroll
  for (int j = 0; j < 8; ++j) { s += xv[j]; s2 += xv[j] * xv[j]; }
#pragma unroll
  for (int m = 1; m < 64; m <<= 1) { s += __shfl_xor(s, m, 64); s2 += __shfl_xor(s2, m, 64); }
  float mu  = s * (1.f / 512.f);
  float var = s2 * (1.f / 512.f) - mu * mu;
  float rs  = rsqrtf(var + 1e-5f);
  const float* Sp = lnS + 5 * 512 + lane * 8;
  const float* Bp = lnB + 5 * 512 + lane * 8;
  const float* wp = ow + lane * 8;
  float acc = 0.f;
#pragma unroll
  for (int j = 0; j < 8; ++j)
    acc += ((xv[j] - mu) * rs * Sp[j] + Bp[j]) * wp[j];
#pragma unroll
  for (int m = 1; m < 64; m <<= 1) acc += __shfl_xor(acc, m, 64);
  if (lane == 0) y[row] = acc + ob[0];
}

extern "C" void kernel_launch(void* const* d_in, const int* in_sizes, int n_in,
                              void* d_out, int out_size, void* d_ws, size_t ws_size,
                              hipStream_t stream) {
  (void)in_sizes; (void)n_in; (void)out_size; (void)ws_size;
  const float* x   = (const float*)d_in[0];
  const float* ipw = (const float*)d_in[1];
  const float* ipb = (const float*)d_in[2];
  const float* Wih = (const float*)d_in[3];
  const float* Whh = (const float*)d_in[4];
  const float* bih = (const float*)d_in[5];
  const float* bhh = (const float*)d_in[6];
  const float* lnS = (const float*)d_in[7];
  const float* lnB = (const float*)d_in[8];
  const float* ow  = (const float*)d_in[9];
  const float* ob  = (const float*)d_in[10];
  float* y = (float*)d_out;

  char* ws = (char*)d_ws;
  unsigned* Flg             = (unsigned*)ws;                         // 12 KB (192×64B)
  unsigned* Prog            = (unsigned*)(ws + 16384);               // 12 KB
  float* XP                 = (float*)(ws + 32768);                  // 64 KB
  float* XG0                = (float*)(ws + 98304);                  // 256 KB
  unsigned long long* Hst   = (unsigned long long*)(ws + 360448);    // 384 KB
  unsigned long long* Roll  = (unsigned long long*)(ws + 753664);    // 640 KB
  unsigned long long* Part  = (unsigned long long*)(ws + 1409024);   // 320 KB
  unsigned* RB              = (unsigned*)(ws + 2097152);             // 67.1 MB

  hipMemsetAsync(ws, 0, 32768, stream);       // Flg + Prog
  k_inproj<<<64, 256, 0, stream>>>(x, ipw, ipb, XP);
  k_xg0<<<256, 256, 0, stream>>>(XP, Wih, bih, XG0);
  k_pipe<<<192, 256, 0, stream>>>(Wih, Whh, bih, bhh, lnS, lnB, XG0, XP,
                                  Hst, Roll, Part, RB, Flg, Prog);
  k_lnout<<<16384, 256, 0, stream>>>(RB, lnS, lnB, ow, ob, y);
}